// Round 1
// baseline (451.891 us; speedup 1.0000x reference)
//
#include <hip/hip_runtime.h>
#include <hip/hip_bf16.h>
#include <math.h>

// Problem constants
#define B_DIM 4
#define T_DIM 1024
#define D_DIM 1024
#define M_DIM 16
#define H_DIM 64
#define NT    4096            // B*T
#define NA    17408           // H*M*(M+1)
#define EPSV  1e-5f

typedef __bf16 bf16_t;
typedef __bf16 bf16x4 __attribute__((ext_vector_type(4)));
typedef __bf16 bf16x8 __attribute__((ext_vector_type(8)));
typedef float  f32x4  __attribute__((ext_vector_type(4)));

// ---------------------------------------------------------------------------
// fp32 -> bf16 conversion (grid-stride, float4 vectorized)
// ---------------------------------------------------------------------------
__global__ __launch_bounds__(256) void cvt_kernel(const float* __restrict__ in,
                                                  bf16_t* __restrict__ out, int n4) {
  int idx = blockIdx.x * blockDim.x + threadIdx.x;
  int stride = gridDim.x * blockDim.x;
  for (; idx < n4; idx += stride) {
    float4 v = reinterpret_cast<const float4*>(in)[idx];
    bf16x4 o;
    o[0] = (bf16_t)v.x; o[1] = (bf16_t)v.y; o[2] = (bf16_t)v.z; o[3] = (bf16_t)v.w;
    reinterpret_cast<bf16x4*>(out)[idx] = o;
  }
}

// ---------------------------------------------------------------------------
// RMSNorm: one block (256 thr) per row of 1024; output bf16
// ---------------------------------------------------------------------------
__global__ __launch_bounds__(256) void rmsnorm_kernel(const float* __restrict__ x,
                                                      const float* __restrict__ w,
                                                      bf16_t* __restrict__ h) {
  int row = blockIdx.x;
  int tid = threadIdx.x;
  const float4* xr = reinterpret_cast<const float4*>(x + (size_t)row * D_DIM);
  float4 xv = xr[tid];
  float ss = xv.x * xv.x + xv.y * xv.y + xv.z * xv.z + xv.w * xv.w;
#pragma unroll
  for (int m = 1; m < 64; m <<= 1) ss += __shfl_xor(ss, m, 64);
  __shared__ float red[4];
  int lane = tid & 63, wid = tid >> 6;
  if (lane == 0) red[wid] = ss;
  __syncthreads();
  float tot = red[0] + red[1] + red[2] + red[3];
  float scale = rsqrtf(tot * (1.0f / D_DIM) + EPSV);
  float4 wv = reinterpret_cast<const float4*>(w)[tid];
  bf16x4 o;
  o[0] = (bf16_t)(xv.x * scale * wv.x);
  o[1] = (bf16_t)(xv.y * scale * wv.y);
  o[2] = (bf16_t)(xv.z * scale * wv.z);
  o[3] = (bf16_t)(xv.w * scale * wv.w);
  reinterpret_cast<bf16x4*>(h)[(size_t)row * 256 + tid] = o;
}

// ---------------------------------------------------------------------------
// NT GEMM: C[M,N] = A[M,K] * Bw[N,K]^T   (bf16 in, fp32 accum)
// 128x128 tile, BK=32, 4 waves (2x2), each wave 64x64 via 4x4 mfma 16x16x32.
// OUT_MODE: 0 = f32 out, 1 = bf16 out, 2 = f32 out + residual add
// ---------------------------------------------------------------------------
template <int OUT_MODE>
__global__ __launch_bounds__(256) void gemm_nt_kernel(const bf16_t* __restrict__ A,
                                                      const bf16_t* __restrict__ Bw,
                                                      void* __restrict__ Cout,
                                                      const float* __restrict__ resid,
                                                      int Mdim, int Ndim, int K) {
  constexpr int BM = 128, BN = 128, BK = 32;
  __shared__ bf16_t As[BM * BK];
  __shared__ bf16_t Bs[BN * BK];

  int tid = threadIdx.x;
  int lane = tid & 63;
  int wid = tid >> 6;           // 0..3
  int wm = wid >> 1, wn = wid & 1;
  int bm = blockIdx.x * BM;
  int bn = blockIdx.y * BN;
  int l15 = lane & 15;
  int l4 = lane >> 4;

  f32x4 acc[4][4];
#pragma unroll
  for (int i = 0; i < 4; i++)
#pragma unroll
    for (int j = 0; j < 4; j++) acc[i][j] = (f32x4){0.f, 0.f, 0.f, 0.f};

  const bf16_t* Ag = A + (size_t)bm * K;
  const bf16_t* Bg = Bw + (size_t)bn * K;
  int srow_lane = lane >> 2;          // 0..15
  int scol = (lane & 3) * 8;          // element col offset

  for (int k0 = 0; k0 < K; k0 += BK) {
    // stage A and B tiles: per wave, 2 insts each of 16 rows x 64B
#pragma unroll
    for (int i = 0; i < 2; i++) {
      int rbase = wid * 32 + i * 16;
      int r = rbase + srow_lane;
      __builtin_amdgcn_global_load_lds(
          (const __attribute__((address_space(1))) void*)(Ag + (size_t)r * K + k0 + scol),
          (__attribute__((address_space(3))) void*)(As + rbase * BK), 16, 0, 0);
      __builtin_amdgcn_global_load_lds(
          (const __attribute__((address_space(1))) void*)(Bg + (size_t)r * K + k0 + scol),
          (__attribute__((address_space(3))) void*)(Bs + rbase * BK), 16, 0, 0);
    }
    __syncthreads();

    const bf16x8* Asv = reinterpret_cast<const bf16x8*>(As);
    const bf16x8* Bsv = reinterpret_cast<const bf16x8*>(Bs);
    bf16x8 af[4], bfr[4];
#pragma unroll
    for (int mf = 0; mf < 4; mf++)
      af[mf] = Asv[(wm * 64 + mf * 16 + l15) * 4 + l4];
#pragma unroll
    for (int nf = 0; nf < 4; nf++)
      bfr[nf] = Bsv[(wn * 64 + nf * 16 + l15) * 4 + l4];
#pragma unroll
    for (int mf = 0; mf < 4; mf++)
#pragma unroll
      for (int nf = 0; nf < 4; nf++)
        acc[mf][nf] = __builtin_amdgcn_mfma_f32_16x16x32_bf16(af[mf], bfr[nf], acc[mf][nf], 0, 0, 0);
    __syncthreads();
  }

  // epilogue: C/D layout col = lane&15, row = 4*(lane>>4)+i
#pragma unroll
  for (int mf = 0; mf < 4; mf++)
#pragma unroll
    for (int nf = 0; nf < 4; nf++)
#pragma unroll
      for (int i = 0; i < 4; i++) {
        int row = bm + wm * 64 + mf * 16 + l4 * 4 + i;
        int col = bn + wn * 64 + nf * 16 + l15;
        size_t idx = (size_t)row * Ndim + col;
        float val = acc[mf][nf][i];
        if (OUT_MODE == 0) {
          ((float*)Cout)[idx] = val;
        } else if (OUT_MODE == 1) {
          ((bf16_t*)Cout)[idx] = (bf16_t)val;
        } else {
          ((float*)Cout)[idx] = val + resid[idx];
        }
      }
}

// ---------------------------------------------------------------------------
// Scan kernel: one block (256 thr) per chain (b,h). Chunked:
//  phase A: all 4 waves do softmax of CT timesteps into LDS (A bf16, u f32)
//  phase B: wave 0 runs the sequential recurrence over the chunk
// ---------------------------------------------------------------------------
#define CT 128
__global__ __launch_bounds__(256) void scan_kernel(const bf16_t* __restrict__ logits,
                                                   const float* __restrict__ v,
                                                   bf16_t* __restrict__ y) {
  int chain = blockIdx.x;           // 0..255
  int b = chain >> 6;
  int hh = chain & 63;

  __shared__ bf16_t Ash[CT * 16 * 16];   // [t][i][j]
  __shared__ float ush[CT * 16];         // [t][i]

  int tid = threadIdx.x;
  int lane = tid & 63;
  int wid = tid >> 6;
  int i16 = lane & 15;
  int c4 = lane >> 4;

  float st = 0.f;   // lane holds state[i16] (replicated across 4 quarters)

  for (int t0 = 0; t0 < T_DIM; t0 += CT) {
    // ---------------- phase A: softmax into LDS ----------------
    {
      int t = tid >> 1;           // 0..127
      int half = tid & 1;         // rows half*8 .. half*8+7
      size_t rowbase = (size_t)(b * T_DIM + t0 + t);
      const bf16x8* Lg = reinterpret_cast<const bf16x8*>(logits + rowbase * NA + hh * 272 + half * 136);
      bf16x8 lg[17];
#pragma unroll
      for (int jj = 0; jj < 17; jj++) lg[jj] = Lg[jj];

      // v values for the 8 rows
      const float4* vp = reinterpret_cast<const float4*>(v + rowbase * D_DIM + hh * 16 + half * 8);
      float4 v0 = vp[0], v1 = vp[1];
      float vl[8];
      vl[0] = v0.x; vl[1] = v0.y; vl[2] = v0.z; vl[3] = v0.w;
      vl[4] = v1.x; vl[5] = v1.y; vl[6] = v1.z; vl[7] = v1.w;

#pragma unroll
      for (int ii = 0; ii < 8; ii++) {
        float e[17];
        float mx = -1e30f;
#pragma unroll
        for (int j = 0; j < 17; j++) {
          int flat = ii * 17 + j;
          e[j] = (float)lg[flat >> 3][flat & 7];
          mx = fmaxf(mx, e[j]);
        }
        float s = 0.f;
#pragma unroll
        for (int j = 0; j < 17; j++) {
          e[j] = __expf(e[j] - mx);
          s += e[j];
        }
        float inv = 1.0f / s;
        int i = half * 8 + ii;
        ush[t * 16 + i] = e[0] * inv * vl[ii];
        bf16x8 w0, w1;
#pragma unroll
        for (int j = 0; j < 8; j++) w0[j] = (bf16_t)(e[1 + j] * inv);
#pragma unroll
        for (int j = 0; j < 8; j++) w1[j] = (bf16_t)(e[9 + j] * inv);
        bf16x8* arow = reinterpret_cast<bf16x8*>(&Ash[(t * 16 + i) * 16]);
        arow[0] = w0;
        arow[1] = w1;
      }
    }
    __syncthreads();

    // ---------------- phase B: sequential recurrence (wave 0) ----------------
    if (wid == 0) {
      bf16x4 a4 = *reinterpret_cast<const bf16x4*>(&Ash[(0 * 16 + i16) * 16 + c4 * 4]);
      float uu = ush[i16];
#pragma unroll 1
      for (int t = 0; t < CT; t++) {
        int tn = (t + 1 < CT) ? (t + 1) : t;
        bf16x4 a4n = *reinterpret_cast<const bf16x4*>(&Ash[(tn * 16 + i16) * 16 + c4 * 4]);
        float un = ush[tn * 16 + i16];

        float s0 = __shfl(st, 4 * c4 + 0, 64);
        float s1 = __shfl(st, 4 * c4 + 1, 64);
        float s2 = __shfl(st, 4 * c4 + 2, 64);
        float s3 = __shfl(st, 4 * c4 + 3, 64);
        float p = (float)a4[0] * s0 + (float)a4[1] * s1 + (float)a4[2] * s2 + (float)a4[3] * s3;
        p += __shfl_xor(p, 16, 64);
        p += __shfl_xor(p, 32, 64);
        st = p + uu;

        if (lane < 16)
          y[(size_t)(b * T_DIM + t0 + t) * D_DIM + hh * 16 + i16] = (bf16_t)st;

        a4 = a4n;
        uu = un;
      }
    }
    __syncthreads();
  }
}

// ---------------------------------------------------------------------------
extern "C" void kernel_launch(void* const* d_in, const int* in_sizes, int n_in,
                              void* d_out, int out_size, void* d_ws, size_t ws_size,
                              hipStream_t stream) {
  const float* x      = (const float*)d_in[0];
  const float* norm_w = (const float*)d_in[1];
  const float* W_v    = (const float*)d_in[2];
  const float* W_a    = (const float*)d_in[3];
  const float* W_out  = (const float*)d_in[4];

  char* ws = (char*)d_ws;
  size_t off = 0;
  auto alloc = [&](size_t bytes) {
    void* p = ws + off;
    off += (bytes + 255) & ~(size_t)255;
    return p;
  };
  bf16_t* wv_b = (bf16_t*)alloc((size_t)D_DIM * D_DIM * 2);        // 2 MB
  bf16_t* wa_b = (bf16_t*)alloc((size_t)NA * D_DIM * 2);           // 35.7 MB
  bf16_t* wo_b = (bf16_t*)alloc((size_t)D_DIM * D_DIM * 2);        // 2 MB
  bf16_t* h_b  = (bf16_t*)alloc((size_t)NT * D_DIM * 2);           // 8 MB
  float*  v_f  = (float*)alloc((size_t)NT * D_DIM * 4);            // 16 MB
  bf16_t* lg_b = (bf16_t*)alloc((size_t)NT * NA * 2);              // 142.6 MB
  bf16_t* y_b  = (bf16_t*)alloc((size_t)NT * D_DIM * 2);           // 8 MB

  cvt_kernel<<<1024, 256, 0, stream>>>(W_v, wv_b, D_DIM * D_DIM / 4);
  cvt_kernel<<<1024, 256, 0, stream>>>(W_a, wa_b, NA * D_DIM / 4);
  cvt_kernel<<<1024, 256, 0, stream>>>(W_out, wo_b, D_DIM * D_DIM / 4);

  rmsnorm_kernel<<<NT, 256, 0, stream>>>(x, norm_w, h_b);

  gemm_nt_kernel<0><<<dim3(NT / 128, D_DIM / 128), 256, 0, stream>>>(
      h_b, wv_b, (void*)v_f, nullptr, NT, D_DIM, D_DIM);
  gemm_nt_kernel<1><<<dim3(NT / 128, NA / 128), 256, 0, stream>>>(
      h_b, wa_b, (void*)lg_b, nullptr, NT, NA, D_DIM);

  scan_kernel<<<256, 256, 0, stream>>>(lg_b, v_f, y_b);

  gemm_nt_kernel<2><<<dim3(NT / 128, D_DIM / 128), 256, 0, stream>>>(
      y_b, wo_b, d_out, x, NT, D_DIM, D_DIM);
}

// Round 2
// 443.050 us; speedup vs baseline: 1.0200x; 1.0200x over previous
//
#include <hip/hip_runtime.h>
#include <hip/hip_bf16.h>
#include <math.h>

// Problem constants
#define B_DIM 4
#define T_DIM 1024
#define D_DIM 1024
#define M_DIM 16
#define H_DIM 64
#define NT    4096            // B*T
#define NA    17408           // H*M*(M+1)
#define EPSV  1e-5f

typedef __bf16 bf16_t;
typedef __bf16 bf16x4 __attribute__((ext_vector_type(4)));
typedef __bf16 bf16x8 __attribute__((ext_vector_type(8)));
typedef float  f32x4  __attribute__((ext_vector_type(4)));

// ---------------------------------------------------------------------------
// fp32 -> bf16 conversion (grid-stride, float4 vectorized)
// ---------------------------------------------------------------------------
__global__ __launch_bounds__(256) void cvt_kernel(const float* __restrict__ in,
                                                  bf16_t* __restrict__ out, int n4) {
  int idx = blockIdx.x * blockDim.x + threadIdx.x;
  int stride = gridDim.x * blockDim.x;
  for (; idx < n4; idx += stride) {
    float4 v = reinterpret_cast<const float4*>(in)[idx];
    bf16x4 o;
    o[0] = (bf16_t)v.x; o[1] = (bf16_t)v.y; o[2] = (bf16_t)v.z; o[3] = (bf16_t)v.w;
    reinterpret_cast<bf16x4*>(out)[idx] = o;
  }
}

// ---------------------------------------------------------------------------
// RMSNorm: one block (256 thr) per row of 1024; output bf16
// ---------------------------------------------------------------------------
__global__ __launch_bounds__(256) void rmsnorm_kernel(const float* __restrict__ x,
                                                      const float* __restrict__ w,
                                                      bf16_t* __restrict__ h) {
  int row = blockIdx.x;
  int tid = threadIdx.x;
  const float4* xr = reinterpret_cast<const float4*>(x + (size_t)row * D_DIM);
  float4 xv = xr[tid];
  float ss = xv.x * xv.x + xv.y * xv.y + xv.z * xv.z + xv.w * xv.w;
#pragma unroll
  for (int m = 1; m < 64; m <<= 1) ss += __shfl_xor(ss, m, 64);
  __shared__ float red[4];
  int lane = tid & 63, wid = tid >> 6;
  if (lane == 0) red[wid] = ss;
  __syncthreads();
  float tot = red[0] + red[1] + red[2] + red[3];
  float scale = rsqrtf(tot * (1.0f / D_DIM) + EPSV);
  float4 wv = reinterpret_cast<const float4*>(w)[tid];
  bf16x4 o;
  o[0] = (bf16_t)(xv.x * scale * wv.x);
  o[1] = (bf16_t)(xv.y * scale * wv.y);
  o[2] = (bf16_t)(xv.z * scale * wv.z);
  o[3] = (bf16_t)(xv.w * scale * wv.w);
  reinterpret_cast<bf16x4*>(h)[(size_t)row * 256 + tid] = o;
}

// ---------------------------------------------------------------------------
// NT GEMM: C[M,N] = A[M,K] * Bw[N,K]^T   (bf16 in, fp32 accum)
// 128x128 tile, BK=32, 4 waves (2x2), each wave 64x64 via 4x4 mfma 16x16x32.
// OUT_MODE: 0 = f32 out, 1 = bf16 out, 2 = f32 out + residual add
// XCD-aware block swizzle (bijective when nwg % 8 == 0).
// ---------------------------------------------------------------------------
template <int OUT_MODE>
__global__ __launch_bounds__(256) void gemm_nt_kernel(const bf16_t* __restrict__ A,
                                                      const bf16_t* __restrict__ Bw,
                                                      void* __restrict__ Cout,
                                                      const float* __restrict__ resid,
                                                      int Mdim, int Ndim, int K) {
  constexpr int BM = 128, BN = 128, BK = 32;
  __shared__ bf16_t As[BM * BK];
  __shared__ bf16_t Bs[BN * BK];

  int tid = threadIdx.x;
  int lane = tid & 63;
  int wid = tid >> 6;           // 0..3
  int wm = wid >> 1, wn = wid & 1;

  int gx = gridDim.x;
  int nwg = gx * gridDim.y;
  int bid = blockIdx.y * gx + blockIdx.x;
  if ((nwg & 7) == 0) {
    int cpx = nwg >> 3;
    bid = (bid & 7) * cpx + (bid >> 3);
  }
  int bm = (bid % gx) * BM;
  int bn = (bid / gx) * BN;

  int l15 = lane & 15;
  int l4 = lane >> 4;

  f32x4 acc[4][4];
#pragma unroll
  for (int i = 0; i < 4; i++)
#pragma unroll
    for (int j = 0; j < 4; j++) acc[i][j] = (f32x4){0.f, 0.f, 0.f, 0.f};

  const bf16_t* Ag = A + (size_t)bm * K;
  const bf16_t* Bg = Bw + (size_t)bn * K;
  int srow_lane = lane >> 2;          // 0..15
  int scol = (lane & 3) * 8;          // element col offset

  for (int k0 = 0; k0 < K; k0 += BK) {
#pragma unroll
    for (int i = 0; i < 2; i++) {
      int rbase = wid * 32 + i * 16;
      int r = rbase + srow_lane;
      __builtin_amdgcn_global_load_lds(
          (const __attribute__((address_space(1))) void*)(Ag + (size_t)r * K + k0 + scol),
          (__attribute__((address_space(3))) void*)(As + rbase * BK), 16, 0, 0);
      __builtin_amdgcn_global_load_lds(
          (const __attribute__((address_space(1))) void*)(Bg + (size_t)r * K + k0 + scol),
          (__attribute__((address_space(3))) void*)(Bs + rbase * BK), 16, 0, 0);
    }
    __syncthreads();

    const bf16x8* Asv = reinterpret_cast<const bf16x8*>(As);
    const bf16x8* Bsv = reinterpret_cast<const bf16x8*>(Bs);
    bf16x8 af[4], bfr[4];
#pragma unroll
    for (int mf = 0; mf < 4; mf++)
      af[mf] = Asv[(wm * 64 + mf * 16 + l15) * 4 + l4];
#pragma unroll
    for (int nf = 0; nf < 4; nf++)
      bfr[nf] = Bsv[(wn * 64 + nf * 16 + l15) * 4 + l4];
#pragma unroll
    for (int mf = 0; mf < 4; mf++)
#pragma unroll
      for (int nf = 0; nf < 4; nf++)
        acc[mf][nf] = __builtin_amdgcn_mfma_f32_16x16x32_bf16(af[mf], bfr[nf], acc[mf][nf], 0, 0, 0);
    __syncthreads();
  }

  // epilogue: C/D layout col = lane&15, row = 4*(lane>>4)+i
#pragma unroll
  for (int mf = 0; mf < 4; mf++)
#pragma unroll
    for (int nf = 0; nf < 4; nf++)
#pragma unroll
      for (int i = 0; i < 4; i++) {
        int row = bm + wm * 64 + mf * 16 + l4 * 4 + i;
        int col = bn + wn * 64 + nf * 16 + l15;
        size_t idx = (size_t)row * Ndim + col;
        float val = acc[mf][nf][i];
        if (OUT_MODE == 0) {
          ((float*)Cout)[idx] = val;
        } else if (OUT_MODE == 1) {
          ((bf16_t*)Cout)[idx] = (bf16_t)val;
        } else {
          ((float*)Cout)[idx] = val + resid[idx];
        }
      }
}

// ---------------------------------------------------------------------------
// Scan kernel v2: producer/consumer pipeline.
//   Block = 192 threads: tid 0..127 = softmax producers (2 waves),
//   tid 128..191 = scanner wave. Double-buffered LDS chunks of CT=64 steps.
//   A stored f32 with XOR bank swizzle; state held wave-uniform via readlane.
// ---------------------------------------------------------------------------
#define CT 64
#define NCHUNK (T_DIM / CT)

// LDS float layout:
//   AshF: [2][CT][16][16]  (chunk buf, t, i, j)  with 16B-slot swizzle on j
//   ushF: [2][CT][16]
__device__ __forceinline__ void produce_chunk(const bf16_t* __restrict__ logits,
                                              const float* __restrict__ v,
                                              float* __restrict__ AshF,
                                              float* __restrict__ ushF,
                                              int b, int hh, int c, int buf, int tid) {
  int t = tid >> 1;           // 0..63
  int half = tid & 1;         // rows half*8 .. half*8+7
  size_t rowbase = (size_t)(b * T_DIM + c * CT + t);
  const bf16x8* Lg = reinterpret_cast<const bf16x8*>(logits + rowbase * NA + hh * 272 + half * 136);
  bf16x8 lg[17];
#pragma unroll
  for (int jj = 0; jj < 17; jj++) lg[jj] = Lg[jj];

  const float4* vp = reinterpret_cast<const float4*>(v + rowbase * D_DIM + hh * 16 + half * 8);
  float4 v0 = vp[0], v1 = vp[1];
  float vl[8];
  vl[0] = v0.x; vl[1] = v0.y; vl[2] = v0.z; vl[3] = v0.w;
  vl[4] = v1.x; vl[5] = v1.y; vl[6] = v1.z; vl[7] = v1.w;

#pragma unroll
  for (int ii = 0; ii < 8; ii++) {
    float e[17];
    float mx = -1e30f;
#pragma unroll
    for (int j = 0; j < 17; j++) {
      int flat = ii * 17 + j;
      e[j] = (float)lg[flat >> 3][flat & 7];
      mx = fmaxf(mx, e[j]);
    }
    float s = 0.f;
#pragma unroll
    for (int j = 0; j < 17; j++) {
      e[j] = __expf(e[j] - mx);
      s += e[j];
    }
    float inv = 1.0f / s;
    int i = half * 8 + ii;
    ushF[buf * (CT * 16) + t * 16 + i] = e[0] * inv * vl[ii];
    // A row i: 16 f32, written as 4 f32x4 with slot swizzle (jb ^ ((i>>1)&3))
    int base = buf * (CT * 256) + t * 256 + i * 16;
    int sw = (i >> 1) & 3;
#pragma unroll
    for (int jb = 0; jb < 4; jb++) {
      f32x4 r;
      r[0] = e[1 + jb * 4 + 0] * inv;
      r[1] = e[1 + jb * 4 + 1] * inv;
      r[2] = e[1 + jb * 4 + 2] * inv;
      r[3] = e[1 + jb * 4 + 3] * inv;
      *reinterpret_cast<f32x4*>(&AshF[base + (jb ^ sw) * 4]) = r;
    }
  }
}

__global__ __launch_bounds__(192) void scan_kernel(const bf16_t* __restrict__ logits,
                                                   const float* __restrict__ v,
                                                   bf16_t* __restrict__ y) {
  int chain = blockIdx.x;           // 0..255
  int b = chain >> 6;
  int hh = chain & 63;

  __shared__ float AshF[2 * CT * 256];   // 131072 B
  __shared__ float ushF[2 * CT * 16];    //   8192 B

  int tid = threadIdx.x;

  if (tid < 128) produce_chunk(logits, v, AshF, ushF, b, hh, 0, 0, tid);
  __syncthreads();

  // scanner state (persists across chunks)
  float s[16];
#pragma unroll
  for (int j = 0; j < 16; j++) s[j] = 0.f;

  int lane = tid & 63;
  int i16 = lane & 15;
  int sw = (i16 >> 1) & 3;
  int rowoff = i16 * 16;

  for (int c = 0; c < NCHUNK; ++c) {
    int buf = c & 1;
    if (tid < 128) {
      if (c + 1 < NCHUNK)
        produce_chunk(logits, v, AshF, ushF, b, hh, c + 1, buf ^ 1, tid);
    } else {
      // ---- scanner wave ----
      const float* Ab = AshF + buf * (CT * 256);
      const float* ub = ushF + buf * (CT * 16);
      bf16_t* yp = y + ((size_t)(b * T_DIM + c * CT)) * D_DIM + hh * 16 + i16;

      f32x4 a0 = *reinterpret_cast<const f32x4*>(&Ab[rowoff + ((0 ^ sw) * 4)]);
      f32x4 a1 = *reinterpret_cast<const f32x4*>(&Ab[rowoff + ((1 ^ sw) * 4)]);
      f32x4 a2 = *reinterpret_cast<const f32x4*>(&Ab[rowoff + ((2 ^ sw) * 4)]);
      f32x4 a3 = *reinterpret_cast<const f32x4*>(&Ab[rowoff + ((3 ^ sw) * 4)]);
      float uu = ub[i16];

#pragma unroll 2
      for (int t = 0; t < CT; ++t) {
        int tn = (t < CT - 1) ? t + 1 : t;
        const float* An = Ab + tn * 256;
        f32x4 b0 = *reinterpret_cast<const f32x4*>(&An[rowoff + ((0 ^ sw) * 4)]);
        f32x4 b1 = *reinterpret_cast<const f32x4*>(&An[rowoff + ((1 ^ sw) * 4)]);
        f32x4 b2 = *reinterpret_cast<const f32x4*>(&An[rowoff + ((2 ^ sw) * 4)]);
        f32x4 b3 = *reinterpret_cast<const f32x4*>(&An[rowoff + ((3 ^ sw) * 4)]);
        float un = ub[tn * 16 + i16];

        // dot: 4 independent fma chains
        float q0 = fmaf(a0[1], s[1], a0[0] * s[0]);
        q0 = fmaf(a0[2], s[2], q0);
        q0 = fmaf(a0[3], s[3], q0);
        float q1 = fmaf(a1[1], s[5], a1[0] * s[4]);
        q1 = fmaf(a1[2], s[6], q1);
        q1 = fmaf(a1[3], s[7], q1);
        float q2 = fmaf(a2[1], s[9], a2[0] * s[8]);
        q2 = fmaf(a2[2], s[10], q2);
        q2 = fmaf(a2[3], s[11], q2);
        float q3 = fmaf(a3[1], s[13], a3[0] * s[12]);
        q3 = fmaf(a3[2], s[14], q3);
        q3 = fmaf(a3[3], s[15], q3);
        float p = (q0 + q1) + (q2 + q3) + uu;

        if (lane < 16) yp[(size_t)t * D_DIM] = (bf16_t)p;

        // rebuild uniform state via readlane broadcast (lanes 0..15 hold p_i)
#pragma unroll
        for (int j = 0; j < 16; j++)
          s[j] = __uint_as_float(__builtin_amdgcn_readlane(__float_as_uint(p), j));

        a0 = b0; a1 = b1; a2 = b2; a3 = b3; uu = un;
      }
    }
    __syncthreads();
  }
}

// ---------------------------------------------------------------------------
extern "C" void kernel_launch(void* const* d_in, const int* in_sizes, int n_in,
                              void* d_out, int out_size, void* d_ws, size_t ws_size,
                              hipStream_t stream) {
  const float* x      = (const float*)d_in[0];
  const float* norm_w = (const float*)d_in[1];
  const float* W_v    = (const float*)d_in[2];
  const float* W_a    = (const float*)d_in[3];
  const float* W_out  = (const float*)d_in[4];

  char* ws = (char*)d_ws;
  size_t off = 0;
  auto alloc = [&](size_t bytes) {
    void* p = ws + off;
    off += (bytes + 255) & ~(size_t)255;
    return p;
  };
  bf16_t* wv_b = (bf16_t*)alloc((size_t)D_DIM * D_DIM * 2);        // 2 MB
  bf16_t* wa_b = (bf16_t*)alloc((size_t)NA * D_DIM * 2);           // 35.7 MB
  bf16_t* wo_b = (bf16_t*)alloc((size_t)D_DIM * D_DIM * 2);        // 2 MB
  bf16_t* h_b  = (bf16_t*)alloc((size_t)NT * D_DIM * 2);           // 8 MB
  float*  v_f  = (float*)alloc((size_t)NT * D_DIM * 4);            // 16 MB
  bf16_t* lg_b = (bf16_t*)alloc((size_t)NT * NA * 2);              // 142.6 MB
  bf16_t* y_b  = (bf16_t*)alloc((size_t)NT * D_DIM * 2);           // 8 MB

  cvt_kernel<<<1024, 256, 0, stream>>>(W_v, wv_b, D_DIM * D_DIM / 4);
  cvt_kernel<<<1024, 256, 0, stream>>>(W_a, wa_b, NA * D_DIM / 4);
  cvt_kernel<<<1024, 256, 0, stream>>>(W_out, wo_b, D_DIM * D_DIM / 4);

  rmsnorm_kernel<<<NT, 256, 0, stream>>>(x, norm_w, h_b);

  gemm_nt_kernel<0><<<dim3(NT / 128, D_DIM / 128), 256, 0, stream>>>(
      h_b, wv_b, (void*)v_f, nullptr, NT, D_DIM, D_DIM);
  gemm_nt_kernel<1><<<dim3(NT / 128, NA / 128), 256, 0, stream>>>(
      h_b, wa_b, (void*)lg_b, nullptr, NT, NA, D_DIM);

  scan_kernel<<<256, 192, 0, stream>>>(lg_b, v_f, y_b);

  gemm_nt_kernel<2><<<dim3(NT / 128, D_DIM / 128), 256, 0, stream>>>(
      y_b, wo_b, d_out, x, NT, D_DIM, D_DIM);
}